// Round 7
// baseline (508.771 us; speedup 1.0000x reference)
//
#include <hip/hip_runtime.h>

// Problem constants (from reference setup_inputs)
#define B_  16
#define T_  4096
#define C_  512
#define K_  4
#define C4_ (C_ / 4)          // 128 float4 columns

// Slab kernel geometry: block = (b, 32-ch tile, T-half), owns 2048 timesteps.
#define NW_     8             // waves per block
#define SUBW_   8             // subchunks per wave
#define NSUB_   (NW_ * SUBW_) // 64 subchunks per chunk
#define LSUB_   8             // timesteps per thread per chunk
#define CHUNK_  (NSUB_ * LSUB_)  // 512 timesteps per iteration
#define HALF_   (T_ / 2)         // 2048 per slab
#define NCH_    (HALF_ / CHUNK_) // 4 chunk iterations per slab
#define CT_     32            // channels per block tile
#define NCT_    (C_ / CT_)    // 16 tiles
#define W_      512           // correction window (rows of slab 1)

typedef float f4 __attribute__((ext_vector_type(4)));

__device__ __forceinline__ float sigmoid_clamp(float la) {
    float av = 1.0f / (1.0f + expf(-la));
    return fminf(fmaxf(av, 1e-4f), 1.0f - 1e-4f);
}

__device__ __forceinline__ f4 shflup4(f4 v, int delta) {
    f4 r;
    r.x = __shfl_up(v.x, delta, 64);
    r.y = __shfl_up(v.y, delta, 64);
    r.z = __shfl_up(v.z, delta, 64);
    r.w = __shfl_up(v.w, delta, 64);
    return r;
}

__device__ __forceinline__ f4 powf4(f4 a, float n) {
    f4 r;
    r.x = exp2f(n * log2f(a.x));
    r.y = exp2f(n * log2f(a.y));
    r.z = exp2f(n * log2f(a.z));
    r.w = exp2f(n * log2f(a.w));
    return r;
}

// ======================================================================
// Slab kernel: block-internal parallel scan over 2048 timesteps.
// h=0: exact (seeded with x0), writes end-of-slab carry to ws.
// h=1: provisional zero-seeded (corrected by ema_fix).
// Swizzled so all 16 column tiles of (b,h) share an XCD -> L2 assembles
// full output rows (fixes R5's 1.7x write amplification).
// ======================================================================
__global__ __launch_bounds__(512, 4) void ema_slab(
    const f4* __restrict__ x4,
    const float* __restrict__ logit_alpha,
    const f4* __restrict__ ml4,
    f4* __restrict__ out4,
    f4* __restrict__ carry_ws)
{
    __shared__ f4 POW8[9][K_][8];     // a^(8s)
    __shared__ f4 POW64[9][K_][8];    // a^(64w)
    __shared__ f4 WT[2][NW_][K_][8];  // per-wave chunk totals, double-buffered

    // swizzled decode: wg = (b%8) | (ct<<3) | ((b>>3)<<7) | (h<<8)
    const int wg = blockIdx.x;
    const int b  = (wg & 7) | (((wg >> 7) & 1) << 3);
    const int ct = (wg >> 3) & 15;
    const int h  = (wg >> 8) & 1;

    const int tid  = threadIdx.x;
    const int wv   = tid >> 6;
    const int lane = tid & 63;
    const int subl = lane >> 3;       // subchunk within wave, 0..7
    const int c4l  = lane & 7;        // float4 lane within tile, 0..7
    const int sub  = (wv << 3) | subl;
    const int c4   = ct * 8 + c4l;    // global float4 column

    f4 one  = {1.f, 1.f, 1.f, 1.f};
    f4 zero = {0.f, 0.f, 0.f, 0.f};
    f4 a[K_], oma[K_], m[K_];
#pragma unroll
    for (int k = 0; k < K_; ++k) {
        f4 la = ((const f4*)logit_alpha)[k * C4_ + c4];
        f4 av;
        av.x = sigmoid_clamp(la.x); av.y = sigmoid_clamp(la.y);
        av.z = sigmoid_clamp(la.z); av.w = sigmoid_clamp(la.w);
        a[k] = av; oma[k] = one - av;
    }
#pragma unroll
    for (int ci = 0; ci < 4; ++ci) {
        f4 ml = ml4[c4 * 4 + ci];
        float mx = fmaxf(fmaxf(ml.x, ml.y), fmaxf(ml.z, ml.w));
        float e0 = expf(ml.x - mx), e1 = expf(ml.y - mx);
        float e2 = expf(ml.z - mx), e3 = expf(ml.w - mx);
        float inv = 1.0f / (e0 + e1 + e2 + e3);
        m[0][ci] = e0 * inv; m[1][ci] = e1 * inv;
        m[2][ci] = e2 * inv; m[3][ci] = e3 * inv;
    }

    if (tid < 32) {
        const int kk = tid >> 3, cc = tid & 7;
        f4 av = a[kk];
        f4 A8 = av * av; A8 = A8 * A8; A8 = A8 * A8;       // a^8
        f4 cur = one;
        POW8[0][kk][cc] = cur;
#pragma unroll
        for (int s = 1; s <= 8; ++s) { cur = cur * A8; POW8[s][kk][cc] = cur; }
        f4 A64 = cur;                                       // a^64
        cur = one;
        POW64[0][kk][cc] = cur;
#pragma unroll
        for (int w = 1; w <= 8; ++w) { cur = cur * A64; POW64[w][kk][cc] = cur; }
    }
    __syncthreads();

    const int t0 = h * HALF_;
    const size_t basein = ((size_t)b * T_ + t0) * C4_ + c4;

    f4 Asub[K_], Gw[K_];
#pragma unroll
    for (int k = 0; k < K_; ++k) Asub[k] = POW8[subl][k][c4l];
    if (h == 0) {
        f4 x0 = x4[(size_t)b * T_ * C4_ + c4];     // seed: y[-1] := x[b,0,c]
#pragma unroll
        for (int k = 0; k < K_; ++k) Gw[k] = POW64[wv][k][c4l] * x0;
    } else {
#pragma unroll
        for (int k = 0; k < K_; ++k) Gw[k] = zero; // provisional zero seed
    }

    const int trow = sub * LSUB_;
    f4 xc[LSUB_];
#pragma unroll
    for (int i = 0; i < LSUB_; ++i)
        xc[i] = __builtin_nontemporal_load(&x4[basein + (size_t)(trow + i) * C4_]);

#pragma unroll 1
    for (int ch = 0; ch < NCH_; ++ch) {
        // prefetch next chunk (stays in flight across the barrier below)
        f4 xn[LSUB_];
        if (ch + 1 < NCH_) {
#pragma unroll
            for (int i = 0; i < LSUB_; ++i)
                xn[i] = __builtin_nontemporal_load(
                    &x4[basein + (size_t)((ch + 1) * CHUNK_ + trow + i) * C4_]);
        }

        // zero-init scan over own 8 steps
        f4 s[K_];
#pragma unroll
        for (int k = 0; k < K_; ++k) s[k] = zero;
#pragma unroll
        for (int i = 0; i < LSUB_; ++i) {
            f4 xv = xc[i];
#pragma unroll
            for (int k = 0; k < K_; ++k) s[k] = a[k] * s[k] + oma[k] * xv;
        }

        // wave-level Hillis-Steele over subchunks
#pragma unroll
        for (int st = 0; st < 3; ++st) {
            const int dd = 1 << st;
#pragma unroll
            for (int k = 0; k < K_; ++k) {
                f4 Mv = POW8[dd][k][c4l];
                f4 r  = shflup4(s[k], dd * 8);
                f4 t2 = s[k] + Mv * r;
                s[k] = (subl >= dd) ? t2 : s[k];
            }
        }
        f4 Ils[K_];
#pragma unroll
        for (int k = 0; k < K_; ++k) {
            f4 r = shflup4(s[k], 8);
            Ils[k] = (subl >= 1) ? r : zero;
        }

        const int pb = ch & 1;
        if (subl == 7) {
#pragma unroll
            for (int k = 0; k < K_; ++k) WT[pb][wv][k][c4l] = s[k];
        }
        asm volatile("s_waitcnt lgkmcnt(0)" ::: "memory");
        __builtin_amdgcn_s_barrier();

        // cross-wave Horner
        f4 P[K_], acc[K_], A64r[K_];
#pragma unroll
        for (int k = 0; k < K_; ++k) {
            P[k] = zero; acc[k] = zero; A64r[k] = POW64[1][k][c4l];
        }
#pragma unroll
        for (int w = 0; w < NW_; ++w) {
#pragma unroll
            for (int k = 0; k < K_; ++k) {
                if (w == wv) P[k] = acc[k];
                acc[k] = A64r[k] * acc[k] + WT[pb][w][k][c4l];
            }
        }

        // rescan from registers with correct carry, mix, cached store
        f4 y[K_];
#pragma unroll
        for (int k = 0; k < K_; ++k) y[k] = Asub[k] * (Gw[k] + P[k]) + Ils[k];

        const size_t ob = basein + (size_t)(ch * CHUNK_ + trow) * C4_;
#pragma unroll
        for (int i = 0; i < LSUB_; ++i) {
            f4 xv = xc[i];
            f4 o = zero;
#pragma unroll
            for (int k = 0; k < K_; ++k) {
                y[k] = a[k] * y[k] + oma[k] * xv;
                o = o + m[k] * y[k];
            }
            out4[ob + (size_t)i * C4_] = o;     // cached: L2 merges tiles
        }

        // advance running carry: Gw = a^512 * Gw + a^(64*wv) * chunk_total
#pragma unroll
        for (int k = 0; k < K_; ++k)
            Gw[k] = POW64[NW_][k][c4l] * Gw[k] + POW64[wv][k][c4l] * acc[k];

        if (ch + 1 < NCH_) {
#pragma unroll
            for (int i = 0; i < LSUB_; ++i) xc[i] = xn[i];
        }
    }

    // h=0, wave 0: Gw == exact y[HALF_-1]  -> carry for slab 1 correction
    if (h == 0 && wv == 0 && subl == 0) {
#pragma unroll
        for (int k = 0; k < K_; ++k)
            carry_ws[(((size_t)b * NCT_ + ct) * K_ + k) * 8 + c4l] = Gw[k];
    }
}

// ======================================================================
// Correction: out[b, HALF_+t', c] += sum_k m_k * a_k^(t'+1) * carry_k[c]
// for t' in [0, W_). Beyond W_, a^t' < 6e-3 -> error ~4e-4, negligible.
// grid = B_*16 blocks; block = (b, 32-row band); 512 thr = 4 rows x 128 c4.
// ======================================================================
__global__ __launch_bounds__(512) void ema_fix(
    const float* __restrict__ logit_alpha,
    const f4* __restrict__ ml4,
    const f4* __restrict__ carry_ws,
    f4* __restrict__ out4)
{
    const int bid = blockIdx.x;
    const int b   = bid >> 4;
    const int r0  = (bid & 15) * (W_ / 16);
    const int c4  = threadIdx.x & 127;
    const int rl  = threadIdx.x >> 7;       // 0..3

    f4 one = {1.f, 1.f, 1.f, 1.f};
    f4 a[K_], m[K_];
#pragma unroll
    for (int k = 0; k < K_; ++k) {
        f4 la = ((const f4*)logit_alpha)[k * C4_ + c4];
        a[k].x = sigmoid_clamp(la.x); a[k].y = sigmoid_clamp(la.y);
        a[k].z = sigmoid_clamp(la.z); a[k].w = sigmoid_clamp(la.w);
    }
#pragma unroll
    for (int ci = 0; ci < 4; ++ci) {
        f4 ml = ml4[c4 * 4 + ci];
        float mx = fmaxf(fmaxf(ml.x, ml.y), fmaxf(ml.z, ml.w));
        float e0 = expf(ml.x - mx), e1 = expf(ml.y - mx);
        float e2 = expf(ml.z - mx), e3 = expf(ml.w - mx);
        float inv = 1.0f / (e0 + e1 + e2 + e3);
        m[0][ci] = e0 * inv; m[1][ci] = e1 * inv;
        m[2][ci] = e2 * inv; m[3][ci] = e3 * inv;
    }

    f4 w[K_], a4[K_];
    const float n0 = (float)(r0 + rl + 1);
#pragma unroll
    for (int k = 0; k < K_; ++k) {
        f4 cr = carry_ws[(((size_t)b * NCT_ + (c4 >> 3)) * K_ + k) * 8 + (c4 & 7)];
        w[k] = m[k] * cr * powf4(a[k], n0);
        f4 t2 = a[k] * a[k];
        a4[k] = t2 * t2;
    }
    (void)one;

#pragma unroll
    for (int it = 0; it < (W_ / 16) / 4; ++it) {
        const size_t idx = ((size_t)b * T_ + HALF_ + r0 + rl + it * 4) * C4_ + c4;
        f4 o = out4[idx];
        o = o + w[0] + w[1] + w[2] + w[3];
        out4[idx] = o;
#pragma unroll
        for (int k = 0; k < K_; ++k) w[k] = w[k] * a4[k];
    }
}

extern "C" void kernel_launch(void* const* d_in, const int* in_sizes, int n_in,
                              void* d_out, int out_size, void* d_ws, size_t ws_size,
                              hipStream_t stream) {
    const float* x           = (const float*)d_in[0];
    const float* logit_alpha = (const float*)d_in[1];
    const float* mix_logits  = (const float*)d_in[2];
    float* out = (float*)d_out;
    f4* carry  = (f4*)d_ws;   // 128 KiB

    ema_slab<<<B_ * NCT_ * 2, 512, 0, stream>>>(
        (const f4*)x, logit_alpha, (const f4*)mix_logits, (f4*)out, carry);
    ema_fix<<<B_ * 16, 512, 0, stream>>>(
        logit_alpha, (const f4*)mix_logits, (const f4*)carry, (f4*)out);
}

// Round 8
// 104.630 us; speedup vs baseline: 4.8626x; 4.8626x over previous
//
#include <hip/hip_runtime.h>

// Problem constants (from reference setup_inputs)
#define B_  16
#define T_  4096
#define C_  512
#define K_  4
#define C4_ (C_ / 4)            // 128 float4 columns per row

// Geometry: block = (b, 64-channel tile, T-slab). Grid = 4*16*8 = 512.
#define NW_     8               // waves per block (512 threads)
#define CF4_    16              // float4 columns per tile (64 channels)
#define NCT_    (C4_ / CF4_)    // 8 channel tiles
#define SUBW_   4               // subchunks per wave (64 lanes / 16)
#define LSUB_   4               // timesteps per thread per iteration
#define WROWS_  (SUBW_ * LSUB_) // 16 rows per wave per iteration
#define CHUNK_  (NW_ * WROWS_)  // 128 rows per block-iteration
#define NSLAB_  4
#define SLAB_   (T_ / NSLAB_)   // 1024 rows per slab
#define WARMIT_ 4               // 512 warm-up rows (a_max^512 ~ 6e-3)
#define TOTIT_  (WARMIT_ + SLAB_ / CHUNK_)   // 12 iterations

typedef float f4 __attribute__((ext_vector_type(4)));

__device__ __forceinline__ float sigmoid_clamp(float la) {
    float av = 1.0f / (1.0f + expf(-la));
    return fminf(fmaxf(av, 1e-4f), 1.0f - 1e-4f);
}

__device__ __forceinline__ f4 shflup4(f4 v, int delta) {
    f4 r;
    r.x = __shfl_up(v.x, delta, 64);
    r.y = __shfl_up(v.y, delta, 64);
    r.z = __shfl_up(v.z, delta, 64);
    r.w = __shfl_up(v.w, delta, 64);
    return r;
}

// Single kernel: block-internal parallel scan over its slab, preceded by a
// 512-step warm-up scan (no stores) that converges the EMA state to within
// a^512 of truth. No workspace, no inter-block communication.
// h=0 slabs seed exactly with x[b,0,c] (reference semantics).
__global__ __launch_bounds__(512, 2) void ema_warm(
    const f4* __restrict__ x4,
    const float* __restrict__ logit_alpha,
    const f4* __restrict__ ml4,
    f4* __restrict__ out4)
{
    __shared__ f4 POW4[5][K_][CF4_];   // a^(4s),  s=0..4
    __shared__ f4 POWW[9][K_][CF4_];   // a^(16w), w=0..8
    __shared__ f4 WT[2][NW_][K_][CF4_];// per-wave totals, double-buffered

    const int wg = blockIdx.x;
    const int ct = wg & (NCT_ - 1);
    const int b  = (wg >> 3) & (B_ - 1);
    const int h  = wg >> 7;            // slab 0..3

    const int tid  = threadIdx.x;
    const int wv   = tid >> 6;
    const int lane = tid & 63;
    const int subl = lane >> 4;        // 0..3
    const int c4l  = lane & 15;        // 0..15
    const int sub  = wv * SUBW_ + subl;// 0..31
    const int c4   = ct * CF4_ + c4l;  // global float4 column

    f4 zero = {0.f, 0.f, 0.f, 0.f};
    f4 a[K_], m[K_];
#pragma unroll
    for (int k = 0; k < K_; ++k) {
        f4 la = ((const f4*)logit_alpha)[k * C4_ + c4];
        a[k].x = sigmoid_clamp(la.x); a[k].y = sigmoid_clamp(la.y);
        a[k].z = sigmoid_clamp(la.z); a[k].w = sigmoid_clamp(la.w);
    }
#pragma unroll
    for (int ci = 0; ci < 4; ++ci) {
        f4 ml = ml4[c4 * 4 + ci];
        float mx = fmaxf(fmaxf(ml.x, ml.y), fmaxf(ml.z, ml.w));
        float e0 = expf(ml.x - mx), e1 = expf(ml.y - mx);
        float e2 = expf(ml.z - mx), e3 = expf(ml.w - mx);
        float inv = 1.0f / (e0 + e1 + e2 + e3);
        m[0][ci] = e0 * inv; m[1][ci] = e1 * inv;
        m[2][ci] = e2 * inv; m[3][ci] = e3 * inv;
    }

    // one-time A-power tables (64 builder threads: k x c4l)
    if (tid < K_ * CF4_) {
        const int kk = tid >> 4, cc = tid & 15;
        f4 av = a[kk];
        f4 one = {1.f, 1.f, 1.f, 1.f};
        f4 A4 = av * av; A4 = A4 * A4;           // a^4
        f4 cur = one;
        POW4[0][kk][cc] = cur;
#pragma unroll
        for (int s = 1; s <= 4; ++s) { cur = cur * A4; POW4[s][kk][cc] = cur; }
        f4 A16 = cur;                             // a^16
        cur = one;
        POWW[0][kk][cc] = cur;
#pragma unroll
        for (int w = 1; w <= 8; ++w) { cur = cur * A16; POWW[w][kk][cc] = cur; }
    }
    __syncthreads();

    const int S   = h * SLAB_;
    const int it0 = (h == 0) ? WARMIT_ : 0;
    const int R0  = S - WARMIT_ * CHUNK_;          // R(it) = R0 + it*CHUNK_
    const size_t colbase = (size_t)b * T_ * C4_ + c4;

    // seed: carry into first processed row := x at that row (exact for h=0)
    f4 xseed = x4[colbase + (size_t)(R0 + it0 * CHUNK_) * C4_];
    f4 Gw[K_];
#pragma unroll
    for (int k = 0; k < K_; ++k) Gw[k] = POWW[wv][k][c4l] * xseed;

    const int trow = sub * LSUB_;
    f4 xc[LSUB_];
#pragma unroll
    for (int i = 0; i < LSUB_; ++i)
        xc[i] = __builtin_nontemporal_load(
            &x4[colbase + (size_t)(R0 + it0 * CHUNK_ + trow + i) * C4_]);

#pragma unroll 1
    for (int it = it0; it < TOTIT_; ++it) {
        const int R = R0 + it * CHUNK_;

        // prefetch next iteration's rows (in flight across the barrier)
        f4 xn[LSUB_];
        if (it + 1 < TOTIT_) {
#pragma unroll
            for (int i = 0; i < LSUB_; ++i)
                xn[i] = __builtin_nontemporal_load(
                    &x4[colbase + (size_t)(R + CHUNK_ + trow + i) * C4_]);
        }

        // zero-init scan of own LSUB_ steps:  s = a*(s-x)+x
        f4 s[K_];
#pragma unroll
        for (int k = 0; k < K_; ++k) s[k] = zero;
#pragma unroll
        for (int i = 0; i < LSUB_; ++i) {
            f4 xv = xc[i];
#pragma unroll
            for (int k = 0; k < K_; ++k) s[k] = a[k] * (s[k] - xv) + xv;
        }

        // wave-level Hillis-Steele over 4 subchunks (2 stages)
#pragma unroll
        for (int st = 0; st < 2; ++st) {
            const int dd = 1 << st;
#pragma unroll
            for (int k = 0; k < K_; ++k) {
                f4 Mv = POW4[dd][k][c4l];
                f4 r  = shflup4(s[k], dd * 16);
                f4 t2 = s[k] + Mv * r;
                s[k] = (subl >= dd) ? t2 : s[k];
            }
        }

        const int pb = it & 1;
        if (subl == SUBW_ - 1) {
#pragma unroll
            for (int k = 0; k < K_; ++k) WT[pb][wv][k][c4l] = s[k];
        }
        asm volatile("s_waitcnt lgkmcnt(0)" ::: "memory");
        __builtin_amdgcn_s_barrier();

        // cross-wave Horner over 8 wave totals (A16 = a^16)
        f4 P[K_], acc[K_], A16r[K_];
#pragma unroll
        for (int k = 0; k < K_; ++k) {
            P[k] = zero; acc[k] = zero; A16r[k] = POWW[1][k][c4l];
        }
#pragma unroll
        for (int w = 0; w < NW_; ++w) {
#pragma unroll
            for (int k = 0; k < K_; ++k) {
                if (w == wv) P[k] = acc[k];
                acc[k] = A16r[k] * acc[k] + WT[pb][w][k][c4l];
            }
        }

        if (it >= WARMIT_) {
            // wave-local exclusive prefix for own subchunk
            f4 Ils[K_];
#pragma unroll
            for (int k = 0; k < K_; ++k) {
                f4 r = shflup4(s[k], 16);
                Ils[k] = (subl >= 1) ? r : zero;
            }
            // carry into own subchunk, rescan, mix, store (256B segments)
            f4 y[K_];
#pragma unroll
            for (int k = 0; k < K_; ++k)
                y[k] = POW4[subl][k][c4l] * (Gw[k] + P[k]) + Ils[k];

            const size_t ob = colbase + (size_t)(R + trow) * C4_;
#pragma unroll
            for (int i = 0; i < LSUB_; ++i) {
                f4 xv = xc[i];
                f4 o = zero;
#pragma unroll
                for (int k = 0; k < K_; ++k) {
                    y[k] = a[k] * (y[k] - xv) + xv;
                    o = o + m[k] * y[k];
                }
                __builtin_nontemporal_store(o, &out4[ob + (size_t)i * C4_]);
            }
        }

        // advance running carry: Gw = a^128 * Gw + a^(16*wv) * chunk_total
#pragma unroll
        for (int k = 0; k < K_; ++k)
            Gw[k] = POWW[8][k][c4l] * Gw[k] + POWW[wv][k][c4l] * acc[k];

        if (it + 1 < TOTIT_) {
#pragma unroll
            for (int i = 0; i < LSUB_; ++i) xc[i] = xn[i];
        }
    }
}

extern "C" void kernel_launch(void* const* d_in, const int* in_sizes, int n_in,
                              void* d_out, int out_size, void* d_ws, size_t ws_size,
                              hipStream_t stream) {
    const float* x           = (const float*)d_in[0];
    const float* logit_alpha = (const float*)d_in[1];
    const float* mix_logits  = (const float*)d_in[2];
    float* out = (float*)d_out;

    ema_warm<<<NSLAB_ * B_ * NCT_, 512, 0, stream>>>(
        (const f4*)x, logit_alpha, (const f4*)mix_logits, (f4*)out);
}